// Round 2
// baseline (2575.076 us; speedup 1.0000x reference)
//
#include <hip/hip_runtime.h>

#define Bq 2048
#define Nn 65536
#define Aa 512
#define Dd 512
#define TK 8
#define NSPLIT 32
#define NSLICE 2048   // Nn / NSPLIT
#define NEG_BIG (-1e38f)

__device__ __forceinline__ float wave_reduce_sum(float v) {
  #pragma unroll
  for (int o = 32; o > 0; o >>= 1) v += __shfl_down(v, o, 64);
  return v;
}

// ---------------- Kernel 1: proj = query @ W.T + b  ([2048][512]) ----------------
__global__ __launch_bounds__(256)
void proj_kernel(const float* __restrict__ query, const float* __restrict__ W,
                 const float* __restrict__ bias, float* __restrict__ proj) {
  __shared__ float Qs[32][64];
  __shared__ float Ws[32][64];
  const int obase = blockIdx.x * 64;
  const int qbase = blockIdx.y * 64;
  const int tid = threadIdx.x;
  const int ty = tid >> 4, tx = tid & 15;
  const int r0 = ty * 4, c0 = tx * 4;
  float acc[4][4] = {};
  for (int kc = 0; kc < Aa; kc += 32) {
    __syncthreads();
    #pragma unroll
    for (int i = 0; i < 2; ++i) {
      int f4 = tid + i * 256;
      int row = f4 >> 3, k4 = (f4 & 7) * 4;
      float4 qv = *reinterpret_cast<const float4*>(&query[(size_t)(qbase + row) * Aa + kc + k4]);
      Qs[k4 + 0][row] = qv.x; Qs[k4 + 1][row] = qv.y; Qs[k4 + 2][row] = qv.z; Qs[k4 + 3][row] = qv.w;
      float4 wv = *reinterpret_cast<const float4*>(&W[(size_t)(obase + row) * Aa + kc + k4]);
      Ws[k4 + 0][row] = wv.x; Ws[k4 + 1][row] = wv.y; Ws[k4 + 2][row] = wv.z; Ws[k4 + 3][row] = wv.w;
    }
    __syncthreads();
    #pragma unroll
    for (int k = 0; k < 32; ++k) {
      float4 qa = *reinterpret_cast<const float4*>(&Qs[k][r0]);
      float4 wa = *reinterpret_cast<const float4*>(&Ws[k][c0]);
      float qv[4] = {qa.x, qa.y, qa.z, qa.w};
      float wv[4] = {wa.x, wa.y, wa.z, wa.w};
      #pragma unroll
      for (int i = 0; i < 4; ++i)
        #pragma unroll
        for (int j = 0; j < 4; ++j)
          acc[i][j] = fmaf(qv[i], wv[j], acc[i][j]);
    }
  }
  float4 bv = *reinterpret_cast<const float4*>(&bias[obase + c0]);
  #pragma unroll
  for (int i = 0; i < 4; ++i) {
    float4 o;
    o.x = acc[i][0] + bv.x; o.y = acc[i][1] + bv.y;
    o.z = acc[i][2] + bv.z; o.w = acc[i][3] + bv.w;
    *reinterpret_cast<float4*>(&proj[(size_t)(qbase + r0 + i) * Aa + obase + c0]) = o;
  }
}

// ---------------- Kernel 2: L2-normalize rows of proj in place ----------------
__global__ __launch_bounds__(256)
void norm_rows_kernel(float* __restrict__ proj) {
  const int row = blockIdx.x;
  const int tid = threadIdx.x;
  float2 v = *reinterpret_cast<float2*>(&proj[(size_t)row * Aa + tid * 2]);
  float ss = v.x * v.x + v.y * v.y;
  __shared__ float red[4];
  ss = wave_reduce_sum(ss);
  if ((tid & 63) == 0) red[tid >> 6] = ss;
  __syncthreads();
  float tot = red[0] + red[1] + red[2] + red[3];
  float scale = 1.0f / fmaxf(sqrtf(tot), 1e-12f);
  v.x *= scale; v.y *= scale;
  *reinterpret_cast<float2*>(&proj[(size_t)row * Aa + tid * 2]) = v;
}

// ---------------- Kernel 3: inverse norms of addr rows ----------------
__global__ __launch_bounds__(256)
void addr_inv_kernel(const float* __restrict__ addr, float* __restrict__ inv) {
  const int wid = threadIdx.x >> 6, lane = threadIdx.x & 63;
  const int row = blockIdx.x * 4 + wid;
  const float4* p = reinterpret_cast<const float4*>(&addr[(size_t)row * Aa + lane * 8]);
  float4 a = p[0], b = p[1];
  float ss = a.x * a.x + a.y * a.y + a.z * a.z + a.w * a.w
           + b.x * b.x + b.y * b.y + b.z * b.z + b.w * b.w;
  ss = wave_reduce_sum(ss);
  if (lane == 0) inv[row] = 1.0f / fmaxf(sqrtf(ss), 1e-12f);
}

// ---------------- Kernel 4: fused sim GEMM + per-query top-8 ----------------
// block: 256 threads, tile 128 queries x 128 addrs, K=512 in chunks of 32.
// grid: (NSPLIT, Bq/128). Thread t (<128) owns query-row t's running top-8.
__global__ __launch_bounds__(256, 2)
void sim_topk_kernel(const float* __restrict__ q, const float* __restrict__ addr,
                     const float* __restrict__ inv, float* __restrict__ cand_val,
                     int* __restrict__ cand_idx) {
  __shared__ float Qs[32][128];
  __shared__ float As[32][128];
  __shared__ float stage[128][33];
  const int ns = blockIdx.x;
  const int qbase = blockIdx.y * 128;
  const int nbase0 = ns * NSLICE;
  const int tid = threadIdx.x;
  const int ty = tid >> 4, tx = tid & 15;
  const int r0 = ty * 8, c0 = tx * 8;

  float tv[TK]; int ti[TK];
  #pragma unroll
  for (int s = 0; s < TK; ++s) { tv[s] = NEG_BIG; ti[s] = 0x7FFFFFFF; }
  float thresh = NEG_BIG;

  for (int nt = 0; nt < NSLICE / 128; ++nt) {
    const int nbase = nbase0 + nt * 128;
    float acc[8][8];
    #pragma unroll
    for (int i = 0; i < 8; ++i)
      #pragma unroll
      for (int j = 0; j < 8; ++j) acc[i][j] = 0.0f;

    for (int kc = 0; kc < Aa; kc += 32) {
      __syncthreads();
      // 128 rows x 32 k = 1024 float4s -> 4 iterations of 256 threads (R1 fix: was i<2)
      #pragma unroll
      for (int i = 0; i < 4; ++i) {
        int f4 = tid + i * 256;
        int row = f4 >> 3, k4 = (f4 & 7) * 4;
        float4 qv = *reinterpret_cast<const float4*>(&q[(size_t)(qbase + row) * Aa + kc + k4]);
        Qs[k4 + 0][row] = qv.x; Qs[k4 + 1][row] = qv.y; Qs[k4 + 2][row] = qv.z; Qs[k4 + 3][row] = qv.w;
        float4 av = *reinterpret_cast<const float4*>(&addr[(size_t)(nbase + row) * Aa + kc + k4]);
        As[k4 + 0][row] = av.x; As[k4 + 1][row] = av.y; As[k4 + 2][row] = av.z; As[k4 + 3][row] = av.w;
      }
      __syncthreads();
      #pragma unroll
      for (int k = 0; k < 32; ++k) {
        float qv[8], av[8];
        *reinterpret_cast<float4*>(&qv[0]) = *reinterpret_cast<const float4*>(&Qs[k][r0]);
        *reinterpret_cast<float4*>(&qv[4]) = *reinterpret_cast<const float4*>(&Qs[k][r0 + 4]);
        *reinterpret_cast<float4*>(&av[0]) = *reinterpret_cast<const float4*>(&As[k][c0]);
        *reinterpret_cast<float4*>(&av[4]) = *reinterpret_cast<const float4*>(&As[k][c0 + 4]);
        #pragma unroll
        for (int i = 0; i < 8; ++i)
          #pragma unroll
          for (int j = 0; j < 8; ++j)
            acc[i][j] = fmaf(qv[i], av[j], acc[i][j]);
      }
    }

    // epilogue: stage 32 columns at a time, scaled by inv_norm; scan per-row top-8
    for (int ch = 0; ch < 4; ++ch) {
      __syncthreads();
      if ((tx >> 2) == ch) {
        int sc = c0 - ch * 32;
        #pragma unroll
        for (int j = 0; j < 8; ++j) {
          float s = inv[nbase + c0 + j];
          #pragma unroll
          for (int i = 0; i < 8; ++i)
            stage[r0 + i][sc + j] = acc[i][j] * s;
        }
      }
      __syncthreads();
      if (tid < 128) {
        int gb = nbase + ch * 32;
        for (int j = 0; j < 32; ++j) {
          float v = stage[tid][j];
          if (v > thresh) {
            // find min value among slots, replace first matching slot (static indexing)
            float mv = tv[0];
            #pragma unroll
            for (int s = 1; s < TK; ++s) mv = fminf(mv, tv[s]);
            bool done = false;
            #pragma unroll
            for (int s = 0; s < TK; ++s) {
              if (!done && tv[s] == mv) { tv[s] = v; ti[s] = gb + j; done = true; }
            }
            thresh = tv[0];
            #pragma unroll
            for (int s = 1; s < TK; ++s) thresh = fminf(thresh, tv[s]);
          }
        }
      }
    }
  }

  if (tid < 128) {
    size_t base = ((size_t)(qbase + tid) * NSPLIT + ns) * TK;
    #pragma unroll
    for (int s = 0; s < TK; ++s) { cand_val[base + s] = tv[s]; cand_idx[base + s] = ti[s]; }
  }
}

// ---------------- Kernel 5: merge candidates, softmax, weighted gather ----------------
__global__ __launch_bounds__(256)
void merge_out_kernel(const float* __restrict__ cand_val, const int* __restrict__ cand_idx,
                      const float* __restrict__ data, float* __restrict__ out) {
  const int qrow = blockIdx.x;
  const int tid = threadIdx.x;
  __shared__ float fw[TK];
  __shared__ int fi[TK];
  if (tid == 0) {
    float bv[TK]; int bi[TK];
    #pragma unroll
    for (int s = 0; s < TK; ++s) { bv[s] = NEG_BIG; bi[s] = 0x7FFFFFFF; }
    const float* cv = &cand_val[(size_t)qrow * NSPLIT * TK];
    const int* ci = &cand_idx[(size_t)qrow * NSPLIT * TK];
    for (int c = 0; c < NSPLIT * TK; ++c) {
      float v = cv[c]; int idx = ci[c];
      int ws = 0;
      for (int s = 1; s < TK; ++s)
        if (bv[s] < bv[ws] || (bv[s] == bv[ws] && bi[s] > bi[ws])) ws = s;
      if (v > bv[ws] || (v == bv[ws] && idx < bi[ws])) { bv[ws] = v; bi[ws] = idx; }
    }
    float m = bv[0];
    #pragma unroll
    for (int s = 1; s < TK; ++s) m = fmaxf(m, bv[s]);
    float w[TK]; float sum = 0.0f;
    #pragma unroll
    for (int s = 0; s < TK; ++s) { w[s] = expf(10.0f * (bv[s] - m)); sum += w[s]; }
    float rs = 1.0f / sum;
    #pragma unroll
    for (int s = 0; s < TK; ++s) { fw[s] = w[s] * rs; fi[s] = bi[s]; }
  }
  __syncthreads();
  float o0 = 0.0f, o1 = 0.0f;
  #pragma unroll
  for (int s = 0; s < TK; ++s) {
    float w = fw[s];
    float2 v = *reinterpret_cast<const float2*>(&data[(size_t)fi[s] * Dd + tid * 2]);
    o0 = fmaf(w, v.x, o0); o1 = fmaf(w, v.y, o1);
  }
  *reinterpret_cast<float2*>(&out[(size_t)qrow * Dd + tid * 2]) = float2{o0, o1};
}

extern "C" void kernel_launch(void* const* d_in, const int* in_sizes, int n_in,
                              void* d_out, int out_size, void* d_ws, size_t ws_size,
                              hipStream_t stream) {
  (void)in_sizes; (void)n_in; (void)out_size; (void)ws_size;
  const float* query = (const float*)d_in[0];
  const float* addr  = (const float*)d_in[1];
  const float* data  = (const float*)d_in[2];
  const float* W     = (const float*)d_in[3];
  const float* bias  = (const float*)d_in[4];
  float* out = (float*)d_out;

  char* ws = (char*)d_ws;
  float* q    = (float*)ws;                                            // 4 MB
  float* inv  = (float*)(ws + (size_t)Bq * Aa * 4);                    // 256 KB
  float* cval = (float*)(ws + (size_t)Bq * Aa * 4 + (size_t)Nn * 4);   // 2 MB
  int*   cidx = (int*)  (ws + (size_t)Bq * Aa * 4 + (size_t)Nn * 4
                            + (size_t)Bq * NSPLIT * TK * 4);           // 2 MB

  proj_kernel<<<dim3(Aa / 64, Bq / 64), 256, 0, stream>>>(query, W, bias, q);
  norm_rows_kernel<<<Bq, 256, 0, stream>>>(q);
  addr_inv_kernel<<<Nn / 4, 256, 0, stream>>>(addr, inv);
  sim_topk_kernel<<<dim3(NSPLIT, Bq / 128), 256, 0, stream>>>(q, addr, inv, cval, cidx);
  merge_out_kernel<<<Bq, 256, 0, stream>>>(cval, cidx, data, out);
}

// Round 4
// 727.705 us; speedup vs baseline: 3.5386x; 3.5386x over previous
//
#include <hip/hip_runtime.h>

#define Bq 2048
#define Nn 65536
#define Aa 512
#define Dd 512
#define TK 8
#define NSPLIT 32
#define NSLICE 2048     // Nn / NSPLIT
#define MSPLIT 8        // candidates kept per (split, column-half)
#define NCAND (NSPLIT * 2 * MSPLIT)   // 512 per query
#define RESC 16         // rescored candidates per query
#define NEG_BIG (-1e38f)

typedef __attribute__((ext_vector_type(8))) short short8v;   // 8 bf16
typedef __attribute__((ext_vector_type(4))) float float4v;   // MFMA acc

__device__ __forceinline__ float wave_reduce_sum(float v) {
  #pragma unroll
  for (int o = 32; o > 0; o >>= 1) v += __shfl_down(v, o, 64);
  return v;
}

__device__ __forceinline__ unsigned short f2bf(float f) {  // RNE fp32->bf16
  unsigned int u = __float_as_uint(f);
  unsigned int r = (u + 0x7fffu + ((u >> 16) & 1u)) >> 16;
  return (unsigned short)r;
}

__device__ __forceinline__ void async16(const void* g, void* l) {
  __builtin_amdgcn_global_load_lds((const __attribute__((address_space(1))) void*)g,
                                   (__attribute__((address_space(3))) void*)l, 16, 0, 0);
}

// ---------------- Kernel 1: proj = query @ W.T + b ----------------
__global__ __launch_bounds__(256)
void proj_kernel(const float* __restrict__ query, const float* __restrict__ W,
                 const float* __restrict__ bias, float* __restrict__ proj) {
  __shared__ float Qs[32][64];
  __shared__ float Ws[32][64];
  const int obase = blockIdx.x * 64;
  const int qbase = blockIdx.y * 64;
  const int tid = threadIdx.x;
  const int ty = tid >> 4, tx = tid & 15;
  const int r0 = ty * 4, c0 = tx * 4;
  float acc[4][4] = {};
  for (int kc = 0; kc < Aa; kc += 32) {
    __syncthreads();
    #pragma unroll
    for (int i = 0; i < 2; ++i) {
      int f4 = tid + i * 256;
      int row = f4 >> 3, k4 = (f4 & 7) * 4;
      float4 qv = *reinterpret_cast<const float4*>(&query[(size_t)(qbase + row) * Aa + kc + k4]);
      Qs[k4 + 0][row] = qv.x; Qs[k4 + 1][row] = qv.y; Qs[k4 + 2][row] = qv.z; Qs[k4 + 3][row] = qv.w;
      float4 wv = *reinterpret_cast<const float4*>(&W[(size_t)(obase + row) * Aa + kc + k4]);
      Ws[k4 + 0][row] = wv.x; Ws[k4 + 1][row] = wv.y; Ws[k4 + 2][row] = wv.z; Ws[k4 + 3][row] = wv.w;
    }
    __syncthreads();
    #pragma unroll
    for (int k = 0; k < 32; ++k) {
      float4 qa = *reinterpret_cast<const float4*>(&Qs[k][r0]);
      float4 wa = *reinterpret_cast<const float4*>(&Ws[k][c0]);
      float qv[4] = {qa.x, qa.y, qa.z, qa.w};
      float wv[4] = {wa.x, wa.y, wa.z, wa.w};
      #pragma unroll
      for (int i = 0; i < 4; ++i)
        #pragma unroll
        for (int j = 0; j < 4; ++j)
          acc[i][j] = fmaf(qv[i], wv[j], acc[i][j]);
    }
  }
  float4 bv = *reinterpret_cast<const float4*>(&bias[obase + c0]);
  #pragma unroll
  for (int i = 0; i < 4; ++i) {
    float4 o;
    o.x = acc[i][0] + bv.x; o.y = acc[i][1] + bv.y;
    o.z = acc[i][2] + bv.z; o.w = acc[i][3] + bv.w;
    *reinterpret_cast<float4*>(&proj[(size_t)(qbase + r0 + i) * Aa + obase + c0]) = o;
  }
}

// ---------------- Kernel 2: normalize q rows in place, emit bf16 copy ----------------
__global__ __launch_bounds__(256)
void norm_rows_q_kernel(float* __restrict__ proj, unsigned short* __restrict__ qb) {
  const int row = blockIdx.x;
  const int tid = threadIdx.x;
  float2 v = *reinterpret_cast<float2*>(&proj[(size_t)row * Aa + tid * 2]);
  float ss = v.x * v.x + v.y * v.y;
  __shared__ float red[4];
  ss = wave_reduce_sum(ss);
  if ((tid & 63) == 0) red[tid >> 6] = ss;
  __syncthreads();
  float tot = red[0] + red[1] + red[2] + red[3];
  float scale = 1.0f / fmaxf(sqrtf(tot), 1e-12f);
  v.x *= scale; v.y *= scale;
  *reinterpret_cast<float2*>(&proj[(size_t)row * Aa + tid * 2]) = v;
  unsigned int packed = (unsigned int)f2bf(v.x) | ((unsigned int)f2bf(v.y) << 16);
  *reinterpret_cast<unsigned int*>(&qb[(size_t)row * Aa + tid * 2]) = packed;
}

// ---------------- Kernel 3: inverse norms of addr rows ----------------
__global__ __launch_bounds__(256)
void addr_inv_kernel(const float* __restrict__ addr, float* __restrict__ inv) {
  const int wid = threadIdx.x >> 6, lane = threadIdx.x & 63;
  const int row = blockIdx.x * 4 + wid;
  const float4* p = reinterpret_cast<const float4*>(&addr[(size_t)row * Aa + lane * 8]);
  float4 a = p[0], b = p[1];
  float ss = a.x * a.x + a.y * a.y + a.z * a.z + a.w * a.w
           + b.x * b.x + b.y * b.y + b.z * b.z + b.w * b.w;
  ss = wave_reduce_sum(ss);
  if (lane == 0) inv[row] = 1.0f / fmaxf(sqrtf(ss), 1e-12f);
}

// ---------------- Kernel 4: bf16 MFMA sim GEMM + fused approx top-8 ----------------
// 128x128 tile, BK=32, 4 waves (2x2 of 64x64), mfma_f32_16x16x32_bf16.
// A (queries, bf16) via global_load_lds; B (addr) read fp32, normalized+converted
// on the fly, reg->LDS staged. kslot swizzle phys = logical ^ ((row>>1)&3).
__global__ __launch_bounds__(256)
void sim_topk_mfma(const unsigned short* __restrict__ qb,
                   const float* __restrict__ addrf,
                   const float* __restrict__ inv,
                   unsigned int* __restrict__ cand) {
  __shared__ __align__(16) unsigned short Asb[128 * 32];
  __shared__ __align__(16) unsigned short Bsb[128 * 32];
  __shared__ float stage[128][65];

  const int ns = blockIdx.x;
  const int qbase = blockIdx.y * 128;
  const int nbase0 = ns * NSLICE;
  const int tid = threadIdx.x;
  const int lane = tid & 63;
  const int wid = tid >> 6;
  const int wr = wid >> 1, wc = wid & 1;
  const int l15 = lane & 15, l4 = lane >> 4;

  // A staging (glld): 512 granule-slots; dest linear in f, source granule = phys ^ swz(row)
  const int f0 = tid, f1 = tid + 256;
  const int row0 = f0 >> 2, kl0 = (f0 & 3) ^ ((row0 >> 1) & 3);
  const int row1 = f1 >> 2, kl1 = (f1 & 3) ^ ((row1 >> 1) & 3);

  // B staging: thread t stages row brow, k-half bh (16 floats -> 2 bf16 granules)
  const int brow = tid >> 1, bh = tid & 1;
  const int bswz = (brow >> 1) & 3;
  const int bg0 = (bh * 2) ^ bswz, bg1 = (bh * 2 + 1) ^ bswz;

  float tv[MSPLIT]; int ti[MSPLIT];
  #pragma unroll
  for (int s = 0; s < MSPLIT; ++s) { tv[s] = -2.0f; ti[s] = 0xFFFF; }
  float th = -2.0f;

  for (int nt = 0; nt < NSLICE / 128; ++nt) {
    const int nbase = nbase0 + nt * 128;
    const float iv = inv[nbase + brow];
    float4v acc[4][4];
    #pragma unroll
    for (int m = 0; m < 4; ++m)
      #pragma unroll
      for (int n = 0; n < 4; ++n) acc[m][n] = (float4v)0.0f;

    for (int kc = 0; kc < Aa; kc += 32) {
      // issue B fp32 loads before the barrier (latency overlaps prior phase tail)
      const float4* bp = reinterpret_cast<const float4*>(&addrf[(size_t)(nbase + brow) * Aa + kc + bh * 16]);
      float4 c0 = bp[0], c1 = bp[1], c2 = bp[2], c3 = bp[3];
      __syncthreads();  // prev phase's LDS reads done; safe to overwrite
      async16(&qb[(size_t)(qbase + row0) * Aa + kc + kl0 * 8], &Asb[f0 * 8]);
      async16(&qb[(size_t)(qbase + row1) * Aa + kc + kl1 * 8], &Asb[f1 * 8]);
      short8v w0, w1;
      w0[0] = (short)f2bf(c0.x * iv); w0[1] = (short)f2bf(c0.y * iv);
      w0[2] = (short)f2bf(c0.z * iv); w0[3] = (short)f2bf(c0.w * iv);
      w0[4] = (short)f2bf(c1.x * iv); w0[5] = (short)f2bf(c1.y * iv);
      w0[6] = (short)f2bf(c1.z * iv); w0[7] = (short)f2bf(c1.w * iv);
      w1[0] = (short)f2bf(c2.x * iv); w1[1] = (short)f2bf(c2.y * iv);
      w1[2] = (short)f2bf(c2.z * iv); w1[3] = (short)f2bf(c2.w * iv);
      w1[4] = (short)f2bf(c3.x * iv); w1[5] = (short)f2bf(c3.y * iv);
      w1[6] = (short)f2bf(c3.z * iv); w1[7] = (short)f2bf(c3.w * iv);
      *reinterpret_cast<short8v*>(&Bsb[brow * 32 + bg0 * 8]) = w0;
      *reinterpret_cast<short8v*>(&Bsb[brow * 32 + bg1 * 8]) = w1;
      asm volatile("s_waitcnt vmcnt(0)" ::: "memory");  // glld A landed
      __syncthreads();  // + lgkm drain for ds_writes (compiler emits full drain)
      short8v a[4], b[4];
      #pragma unroll
      for (int m = 0; m < 4; ++m) {
        int ra = wr * 64 + m * 16 + l15;
        int kph = l4 ^ ((ra >> 1) & 3);
        a[m] = *reinterpret_cast<const short8v*>(&Asb[ra * 32 + kph * 8]);
      }
      #pragma unroll
      for (int n = 0; n < 4; ++n) {
        int rb = wc * 64 + n * 16 + l15;
        int kph = l4 ^ ((rb >> 1) & 3);
        b[n] = *reinterpret_cast<const short8v*>(&Bsb[rb * 32 + kph * 8]);
      }
      #pragma unroll
      for (int m = 0; m < 4; ++m)
        #pragma unroll
        for (int n = 0; n < 4; ++n)
          acc[m][n] = __builtin_amdgcn_mfma_f32_16x16x32_bf16(a[m], b[n], acc[m][n], 0, 0, 0);
    }

    // epilogue: 2 chunks of 64 cols; C/D layout col=lane&15, row=(lane>>4)*4+reg
    #pragma unroll
    for (int ch = 0; ch < 2; ++ch) {
      __syncthreads();
      if (wc == ch) {
        #pragma unroll
        for (int m = 0; m < 4; ++m)
          #pragma unroll
          for (int n = 0; n < 4; ++n)
            #pragma unroll
            for (int j = 0; j < 4; ++j)
              stage[wr * 64 + m * 16 + l4 * 4 + j][n * 16 + l15] = acc[m][n][j];
      }
      __syncthreads();
      const int r = tid & 127, h = tid >> 7;
      const int gb = nbase + ch * 64 + h * 32;
      #pragma unroll 4
      for (int j = 0; j < 32; ++j) {
        float v = stage[r][h * 32 + j];
        if (v > th) {
          float mv = tv[0];
          #pragma unroll
          for (int s = 1; s < MSPLIT; ++s) mv = fminf(mv, tv[s]);
          bool done = false;
          #pragma unroll
          for (int s = 0; s < MSPLIT; ++s)
            if (!done && tv[s] == mv) { tv[s] = v; ti[s] = gb + j; done = true; }
          th = tv[0];
          #pragma unroll
          for (int s = 1; s < MSPLIT; ++s) th = fminf(th, tv[s]);
        }
      }
    }
  }

  // pack (fixed16 value | idx16) and store
  const int r = tid & 127, h = tid >> 7;
  size_t base = (((size_t)(qbase + r) * NSPLIT + ns) * 2 + h) * MSPLIT;
  #pragma unroll
  for (int s = 0; s < MSPLIT; ++s) {
    unsigned int fx = (unsigned int)(int)((tv[s] + 2.0f) * 16384.0f + 0.5f);
    cand[base + s] = (fx << 16) | (unsigned int)(ti[s] & 0xFFFF);
  }
}

// ---------------- Kernel 5: merge 512 -> approx top-16 -> fp32 rescore -> top-8 -> out ----------------
__global__ __launch_bounds__(256)
void merge_rescore_kernel(const unsigned int* __restrict__ cand,
                          const float* __restrict__ q, const float* __restrict__ addrf,
                          const float* __restrict__ inv, const float* __restrict__ data,
                          float* __restrict__ out) {
  const int qrow = blockIdx.x;
  const int tid = threadIdx.x;
  const int wid = tid >> 6, lane = tid & 63;
  __shared__ int sidx[RESC];
  __shared__ float resc[RESC];
  __shared__ float sw[TK]; __shared__ int sfi[TK];

  if (tid == 0) {
    unsigned int bp[RESC];
    #pragma unroll
    for (int s = 0; s < RESC; ++s) bp[s] = 0u;
    unsigned int th = 0u;
    const unsigned int* cv = &cand[(size_t)qrow * NCAND];
    for (int c = 0; c < NCAND; ++c) {
      unsigned int p = cv[c];
      if (p > th) {
        unsigned int mv = bp[0];
        #pragma unroll
        for (int s = 1; s < RESC; ++s) mv = min(mv, bp[s]);
        bool done = false;
        #pragma unroll
        for (int s = 0; s < RESC; ++s)
          if (!done && bp[s] == mv) { bp[s] = p; done = true; }
        th = bp[0];
        #pragma unroll
        for (int s = 1; s < RESC; ++s) th = min(th, bp[s]);
      }
    }
    #pragma unroll
    for (int s = 0; s < RESC; ++s) sidx[s] = (int)(bp[s] & 0xFFFFu);
  }
  __syncthreads();

  // exact fp32 rescore of 16 candidates: wave w handles c = w*4 + it
  float4 q0 = *reinterpret_cast<const float4*>(&q[(size_t)qrow * Aa + lane * 8]);
  float4 q1 = *reinterpret_cast<const float4*>(&q[(size_t)qrow * Aa + lane * 8 + 4]);
  #pragma unroll
  for (int it = 0; it < RESC / 4; ++it) {
    int c = wid * 4 + it;
    int idx = sidx[c];
    const float4* ap = reinterpret_cast<const float4*>(&addrf[(size_t)idx * Aa + lane * 8]);
    float4 a0 = ap[0], a1 = ap[1];
    float s = q0.x * a0.x + q0.y * a0.y + q0.z * a0.z + q0.w * a0.w
            + q1.x * a1.x + q1.y * a1.y + q1.z * a1.z + q1.w * a1.w;
    s = wave_reduce_sum(s);
    if (lane == 0) resc[c] = s * inv[idx];
  }
  __syncthreads();

  if (tid == 0) {
    float rv[RESC]; int ri[RESC];
    #pragma unroll
    for (int s = 0; s < RESC; ++s) { rv[s] = resc[s]; ri[s] = sidx[s]; }
    float cv8[TK]; int ci8[TK];
    #pragma unroll
    for (int k = 0; k < TK; ++k) {
      float mv = rv[0]; int mi = ri[0];
      #pragma unroll
      for (int s = 1; s < RESC; ++s)
        if (rv[s] > mv || (rv[s] == mv && ri[s] < mi)) { mv = rv[s]; mi = ri[s]; }
      cv8[k] = mv; ci8[k] = mi;
      #pragma unroll
      for (int s = 0; s < RESC; ++s)
        if (ri[s] == mi) rv[s] = NEG_BIG;
    }
    float m = cv8[0];
    float wv[TK]; float sum = 0.0f;
    #pragma unroll
    for (int k = 0; k < TK; ++k) { wv[k] = expf(10.0f * (cv8[k] - m)); sum += wv[k]; }
    float rs = 1.0f / sum;
    #pragma unroll
    for (int k = 0; k < TK; ++k) { sw[k] = wv[k] * rs; sfi[k] = ci8[k]; }
  }
  __syncthreads();

  float o0 = 0.0f, o1 = 0.0f;
  #pragma unroll
  for (int s = 0; s < TK; ++s) {
    float w = sw[s];
    float2 v = *reinterpret_cast<const float2*>(&data[(size_t)sfi[s] * Dd + tid * 2]);
    o0 = fmaf(w, v.x, o0); o1 = fmaf(w, v.y, o1);
  }
  *reinterpret_cast<float2*>(&out[(size_t)qrow * Dd + tid * 2]) = float2{o0, o1};
}

extern "C" void kernel_launch(void* const* d_in, const int* in_sizes, int n_in,
                              void* d_out, int out_size, void* d_ws, size_t ws_size,
                              hipStream_t stream) {
  (void)in_sizes; (void)n_in; (void)out_size; (void)ws_size;
  const float* query = (const float*)d_in[0];
  const float* addr  = (const float*)d_in[1];
  const float* data  = (const float*)d_in[2];
  const float* W     = (const float*)d_in[3];
  const float* bias  = (const float*)d_in[4];
  float* out = (float*)d_out;

  // ws: 8.44 MB total (<= R2-proven 8.25 MB + 0.2; q 4MB | inv 256KB | cand 4MB)
  char* ws = (char*)d_ws;
  size_t off = 0;
  float* q = (float*)(ws + off);            off += (size_t)Bq * Aa * 4;
  float* inv = (float*)(ws + off);          off += (size_t)Nn * 4;
  unsigned int* cand = (unsigned int*)(ws + off);
  // bf16 q lives in d_out (2MB of 4MB); merge_rescore overwrites d_out afterwards
  unsigned short* qb = (unsigned short*)d_out;

  proj_kernel<<<dim3(Aa / 64, Bq / 64), 256, 0, stream>>>(query, W, bias, q);
  norm_rows_q_kernel<<<Bq, 256, 0, stream>>>(q, qb);
  addr_inv_kernel<<<Nn / 4, 256, 0, stream>>>(addr, inv);
  sim_topk_mfma<<<dim3(NSPLIT, Bq / 128), 256, 0, stream>>>(qb, addr, inv, cand);
  merge_rescore_kernel<<<Bq, 256, 0, stream>>>(cand, q, addr, inv, data, out);
}

// Round 5
// 425.392 us; speedup vs baseline: 6.0534x; 1.7107x over previous
//
#include <hip/hip_runtime.h>

#define Bq 2048
#define Nn 65536
#define Aa 512
#define Dd 512
#define TK 8
#define NSPLIT 64
#define NSLICE 1024     // Nn / NSPLIT
#define MSPLIT 8        // per-thread candidates per (split, col-parity) before end-merge
#define KEEP 8          // packed candidates stored per (query, split)
#define NCAND (NSPLIT * KEEP)   // 512 per query (same ws as R4)
#define RESC 16         // rescored candidates per query
#define NEG_BIG (-1e38f)

typedef __attribute__((ext_vector_type(8))) short short8v;   // 8 bf16
typedef __attribute__((ext_vector_type(4))) float float4v;   // MFMA acc

__device__ __forceinline__ float wave_reduce_sum(float v) {
  #pragma unroll
  for (int o = 32; o > 0; o >>= 1) v += __shfl_down(v, o, 64);
  return v;
}

__device__ __forceinline__ unsigned short f2bf(float f) {  // RNE fp32->bf16
  unsigned int u = __float_as_uint(f);
  unsigned int r = (u + 0x7fffu + ((u >> 16) & 1u)) >> 16;
  return (unsigned short)r;
}

__device__ __forceinline__ unsigned cvt_pk(float lo, float hi) {
  unsigned r;
  asm("v_cvt_pk_bf16_f32 %0, %1, %2" : "=v"(r) : "v"(lo), "v"(hi));
  return r;
}

__device__ __forceinline__ void async16(const void* g, void* l) {
  __builtin_amdgcn_global_load_lds((const __attribute__((address_space(1))) void*)g,
                                   (__attribute__((address_space(3))) void*)l, 16, 0, 0);
}

// ---------------- Kernel 1: proj = query @ W.T + b ----------------
__global__ __launch_bounds__(256)
void proj_kernel(const float* __restrict__ query, const float* __restrict__ W,
                 const float* __restrict__ bias, float* __restrict__ proj) {
  __shared__ float Qs[32][64];
  __shared__ float Ws[32][64];
  const int obase = blockIdx.x * 64;
  const int qbase = blockIdx.y * 64;
  const int tid = threadIdx.x;
  const int ty = tid >> 4, tx = tid & 15;
  const int r0 = ty * 4, c0 = tx * 4;
  float acc[4][4] = {};
  for (int kc = 0; kc < Aa; kc += 32) {
    __syncthreads();
    #pragma unroll
    for (int i = 0; i < 2; ++i) {
      int f4 = tid + i * 256;
      int row = f4 >> 3, k4 = (f4 & 7) * 4;
      float4 qv = *reinterpret_cast<const float4*>(&query[(size_t)(qbase + row) * Aa + kc + k4]);
      Qs[k4 + 0][row] = qv.x; Qs[k4 + 1][row] = qv.y; Qs[k4 + 2][row] = qv.z; Qs[k4 + 3][row] = qv.w;
      float4 wv = *reinterpret_cast<const float4*>(&W[(size_t)(obase + row) * Aa + kc + k4]);
      Ws[k4 + 0][row] = wv.x; Ws[k4 + 1][row] = wv.y; Ws[k4 + 2][row] = wv.z; Ws[k4 + 3][row] = wv.w;
    }
    __syncthreads();
    #pragma unroll
    for (int k = 0; k < 32; ++k) {
      float4 qa = *reinterpret_cast<const float4*>(&Qs[k][r0]);
      float4 wa = *reinterpret_cast<const float4*>(&Ws[k][c0]);
      float qv[4] = {qa.x, qa.y, qa.z, qa.w};
      float wv[4] = {wa.x, wa.y, wa.z, wa.w};
      #pragma unroll
      for (int i = 0; i < 4; ++i)
        #pragma unroll
        for (int j = 0; j < 4; ++j)
          acc[i][j] = fmaf(qv[i], wv[j], acc[i][j]);
    }
  }
  float4 bv = *reinterpret_cast<const float4*>(&bias[obase + c0]);
  #pragma unroll
  for (int i = 0; i < 4; ++i) {
    float4 o;
    o.x = acc[i][0] + bv.x; o.y = acc[i][1] + bv.y;
    o.z = acc[i][2] + bv.z; o.w = acc[i][3] + bv.w;
    *reinterpret_cast<float4*>(&proj[(size_t)(qbase + r0 + i) * Aa + obase + c0]) = o;
  }
}

// ---------------- Kernel 2: normalize q rows in place, emit bf16 copy ----------------
__global__ __launch_bounds__(256)
void norm_rows_q_kernel(float* __restrict__ proj, unsigned short* __restrict__ qb) {
  const int row = blockIdx.x;
  const int tid = threadIdx.x;
  float2 v = *reinterpret_cast<float2*>(&proj[(size_t)row * Aa + tid * 2]);
  float ss = v.x * v.x + v.y * v.y;
  __shared__ float red[4];
  ss = wave_reduce_sum(ss);
  if ((tid & 63) == 0) red[tid >> 6] = ss;
  __syncthreads();
  float tot = red[0] + red[1] + red[2] + red[3];
  float scale = 1.0f / fmaxf(sqrtf(tot), 1e-12f);
  v.x *= scale; v.y *= scale;
  *reinterpret_cast<float2*>(&proj[(size_t)row * Aa + tid * 2]) = v;
  unsigned int packed = (unsigned int)f2bf(v.x) | ((unsigned int)f2bf(v.y) << 16);
  *reinterpret_cast<unsigned int*>(&qb[(size_t)row * Aa + tid * 2]) = packed;
}

// ---------------- Kernel 3: inverse norms of addr rows ----------------
__global__ __launch_bounds__(256)
void addr_inv_kernel(const float* __restrict__ addr, float* __restrict__ inv) {
  const int wid = threadIdx.x >> 6, lane = threadIdx.x & 63;
  const int row = blockIdx.x * 4 + wid;
  const float4* p = reinterpret_cast<const float4*>(&addr[(size_t)row * Aa + lane * 8]);
  float4 a = p[0], b = p[1];
  float ss = a.x * a.x + a.y * a.y + a.z * a.z + a.w * a.w
           + b.x * b.x + b.y * b.y + b.z * b.z + b.w * b.w;
  ss = wave_reduce_sum(ss);
  if (lane == 0) inv[row] = 1.0f / fmaxf(sqrtf(ss), 1e-12f);
}

// ---------------- Kernel 4: bf16 MFMA sim GEMM + fused approx top-8 ----------------
// 128x128 tile, BK=32, 4 waves (2x2 of 64x64), mfma_f32_16x16x32_bf16.
// grid (NSPLIT=64, 16) = 1024 blocks = 4/CU; LDS 33.3 KB.
__global__ __launch_bounds__(256, 4)
void sim_topk_mfma(const unsigned short* __restrict__ qb,
                   const float* __restrict__ addrf,
                   const float* __restrict__ inv,
                   unsigned int* __restrict__ cand) {
  __shared__ __align__(16) unsigned short Asb[128 * 32];
  __shared__ __align__(16) unsigned short Bsb[128 * 32];
  __shared__ float stage[128][33];

  const int ns = blockIdx.x;
  const int qbase = blockIdx.y * 128;
  const int nbase0 = ns * NSLICE;
  const int tid = threadIdx.x;
  const int lane = tid & 63;
  const int wid = tid >> 6;
  const int wr = wid >> 1, wc = wid & 1;
  const int l15 = lane & 15, l4 = lane >> 4;

  // A staging (glld): 512 granule-slots; dest linear in f, src granule = phys ^ swz(row)
  const int f0 = tid, f1 = tid + 256;
  const int row0 = f0 >> 2, kl0 = (f0 & 3) ^ ((row0 >> 1) & 3);
  const int row1 = f1 >> 2, kl1 = (f1 & 3) ^ ((row1 >> 1) & 3);

  // B staging: thread t stages row brow, k-half bh (16 floats -> 2 bf16 granules)
  const int brow = tid >> 1, bh = tid & 1;
  const int bswz = (brow >> 1) & 3;
  const int bg0 = (bh * 2) ^ bswz, bg1 = (bh * 2 + 1) ^ bswz;

  float tv[MSPLIT]; int ti[MSPLIT];
  #pragma unroll
  for (int s = 0; s < MSPLIT; ++s) { tv[s] = -2.0f; ti[s] = 0xFFFF; }
  float th = -2.0f;

  for (int nt = 0; nt < NSLICE / 128; ++nt) {
    const int nbase = nbase0 + nt * 128;
    const float iv = inv[nbase + brow];
    float4v acc[4][4];
    #pragma unroll
    for (int m = 0; m < 4; ++m)
      #pragma unroll
      for (int n = 0; n < 4; ++n) acc[m][n] = (float4v)0.0f;

    for (int kc = 0; kc < Aa; kc += 32) {
      // issue B fp32 loads before the barrier (latency overlaps prior phase tail)
      const float4* bp = reinterpret_cast<const float4*>(&addrf[(size_t)(nbase + brow) * Aa + kc + bh * 16]);
      float4 c0 = bp[0], c1 = bp[1], c2 = bp[2], c3 = bp[3];
      __syncthreads();  // prev phase's LDS reads done; safe to overwrite
      async16(&qb[(size_t)(qbase + row0) * Aa + kc + kl0 * 8], &Asb[f0 * 8]);
      async16(&qb[(size_t)(qbase + row1) * Aa + kc + kl1 * 8], &Asb[f1 * 8]);
      uint4 w0, w1;
      w0.x = cvt_pk(c0.x * iv, c0.y * iv); w0.y = cvt_pk(c0.z * iv, c0.w * iv);
      w0.z = cvt_pk(c1.x * iv, c1.y * iv); w0.w = cvt_pk(c1.z * iv, c1.w * iv);
      w1.x = cvt_pk(c2.x * iv, c2.y * iv); w1.y = cvt_pk(c2.z * iv, c2.w * iv);
      w1.z = cvt_pk(c3.x * iv, c3.y * iv); w1.w = cvt_pk(c3.z * iv, c3.w * iv);
      *reinterpret_cast<uint4*>(&Bsb[brow * 32 + bg0 * 8]) = w0;
      *reinterpret_cast<uint4*>(&Bsb[brow * 32 + bg1 * 8]) = w1;
      asm volatile("s_waitcnt vmcnt(0)" ::: "memory");  // glld A landed
      __syncthreads();  // + lgkm drain for ds_writes
      short8v a[4], b[4];
      #pragma unroll
      for (int m = 0; m < 4; ++m) {
        int ra = wr * 64 + m * 16 + l15;
        int kph = l4 ^ ((ra >> 1) & 3);
        a[m] = *reinterpret_cast<const short8v*>(&Asb[ra * 32 + kph * 8]);
      }
      #pragma unroll
      for (int n = 0; n < 4; ++n) {
        int rb = wc * 64 + n * 16 + l15;
        int kph = l4 ^ ((rb >> 1) & 3);
        b[n] = *reinterpret_cast<const short8v*>(&Bsb[rb * 32 + kph * 8]);
      }
      #pragma unroll
      for (int m = 0; m < 4; ++m)
        #pragma unroll
        for (int n = 0; n < 4; ++n)
          acc[m][n] = __builtin_amdgcn_mfma_f32_16x16x32_bf16(a[m], b[n], acc[m][n], 0, 0, 0);
    }

    // epilogue: 4 chunks of 32 cols; C/D layout col=lane&15, row=(lane>>4)*4+reg
    #pragma unroll
    for (int ch = 0; ch < 4; ++ch) {
      __syncthreads();
      if (wc == (ch >> 1)) {
        #pragma unroll
        for (int m = 0; m < 4; ++m)
          #pragma unroll
          for (int nl = 0; nl < 2; ++nl) {
            int n = (ch & 1) * 2 + nl;
            #pragma unroll
            for (int j = 0; j < 4; ++j)
              stage[wr * 64 + m * 16 + l4 * 4 + j][nl * 16 + l15] = acc[m][n][j];
          }
      }
      __syncthreads();
      const int r = tid & 127, hh = tid >> 7;
      const int gb = nbase + ch * 32 + hh * 16;
      #pragma unroll 4
      for (int j = 0; j < 16; ++j) {
        float v = stage[r][hh * 16 + j];
        if (v > th) {
          float mv = tv[0];
          #pragma unroll
          for (int s = 1; s < MSPLIT; ++s) mv = fminf(mv, tv[s]);
          bool done = false;
          #pragma unroll
          for (int s = 0; s < MSPLIT; ++s)
            if (!done && tv[s] == mv) { tv[s] = v; ti[s] = gb + j; done = true; }
          th = tv[0];
          #pragma unroll
          for (int s = 1; s < MSPLIT; ++s) th = fminf(th, tv[s]);
        }
      }
    }
  }

  // pack (fixed16 value | idx16); end-merge 2 parity buckets -> top-8 per (query,split)
  unsigned pk[MSPLIT];
  #pragma unroll
  for (int s = 0; s < MSPLIT; ++s) {
    unsigned fx = (unsigned)(int)((tv[s] + 2.0f) * 16384.0f + 0.5f);
    pk[s] = (fx << 16) | (unsigned)(ti[s] & 0xFFFF);
  }
  unsigned* mg = reinterpret_cast<unsigned*>(&stage[0][0]);
  __syncthreads();  // all scans done before overwriting stage
  {
    const int r = tid & 127, hh = tid >> 7;
    #pragma unroll
    for (int s = 0; s < MSPLIT; ++s) mg[r * 16 + hh * 8 + s] = pk[s];
  }
  __syncthreads();
  if (tid < 128) {
    unsigned v[16];
    #pragma unroll
    for (int s = 0; s < 16; ++s) v[s] = mg[tid * 16 + s];
    size_t base = ((size_t)(qbase + tid) * NSPLIT + ns) * KEEP;
    #pragma unroll
    for (int k = 0; k < KEEP; ++k) {
      unsigned M = v[0];
      #pragma unroll
      for (int s = 1; s < 16; ++s) M = (v[s] > M) ? v[s] : M;
      cand[base + k] = M;
      #pragma unroll
      for (int s = 0; s < 16; ++s) if (v[s] == M) v[s] = 0u;
    }
  }
}

// ---------------- Kernel 5: merge 512 -> approx top-16 -> fp32 rescore -> top-8 -> out ----------------
__global__ __launch_bounds__(256)
void merge_rescore_kernel(const unsigned int* __restrict__ cand,
                          const float* __restrict__ q, const float* __restrict__ addrf,
                          const float* __restrict__ inv, const float* __restrict__ data,
                          float* __restrict__ out) {
  const int qrow = blockIdx.x;
  const int tid = threadIdx.x;
  const int wid = tid >> 6, lane = tid & 63;
  __shared__ int sidx[RESC];
  __shared__ float resc[RESC];
  __shared__ float sw[TK]; __shared__ int sfi[TK];

  // wave 0: top-16 of 512 packed candidates (64 lanes x 8 regs, 16 reduce-clear iters)
  if (wid == 0) {
    const unsigned* cv = &cand[(size_t)qrow * NCAND];
    uint4 t0 = *reinterpret_cast<const uint4*>(&cv[lane * 8]);
    uint4 t1 = *reinterpret_cast<const uint4*>(&cv[lane * 8 + 4]);
    unsigned v[8] = {t0.x, t0.y, t0.z, t0.w, t1.x, t1.y, t1.z, t1.w};
    #pragma unroll
    for (int it = 0; it < RESC; ++it) {
      unsigned m = v[0];
      #pragma unroll
      for (int s = 1; s < 8; ++s) m = (v[s] > m) ? v[s] : m;
      #pragma unroll
      for (int off = 1; off < 64; off <<= 1) {
        unsigned o_ = (unsigned)__shfl_xor((int)m, off, 64);
        m = (o_ > m) ? o_ : m;
      }
      if (lane == 0) sidx[it] = (int)(m & 0xFFFFu);
      #pragma unroll
      for (int s = 0; s < 8; ++s) if (v[s] == m) v[s] = 0u;
    }
  }
  __syncthreads();

  // exact fp32 rescore of 16 candidates: wave w handles c = w*4 + it
  float4 q0 = *reinterpret_cast<const float4*>(&q[(size_t)qrow * Aa + lane * 8]);
  float4 q1 = *reinterpret_cast<const float4*>(&q[(size_t)qrow * Aa + lane * 8 + 4]);
  #pragma unroll
  for (int it = 0; it < RESC / 4; ++it) {
    int c = wid * 4 + it;
    int idx = sidx[c];
    const float4* ap = reinterpret_cast<const float4*>(&addrf[(size_t)idx * Aa + lane * 8]);
    float4 a0 = ap[0], a1 = ap[1];
    float s = q0.x * a0.x + q0.y * a0.y + q0.z * a0.z + q0.w * a0.w
            + q1.x * a1.x + q1.y * a1.y + q1.z * a1.z + q1.w * a1.w;
    s = wave_reduce_sum(s);
    if (lane == 0) resc[c] = s * inv[idx];
  }
  __syncthreads();

  if (tid == 0) {
    float rv[RESC]; int ri[RESC];
    #pragma unroll
    for (int s = 0; s < RESC; ++s) { rv[s] = resc[s]; ri[s] = sidx[s]; }
    float cv8[TK]; int ci8[TK];
    #pragma unroll
    for (int k = 0; k < TK; ++k) {
      float mv = rv[0]; int mi = ri[0];
      #pragma unroll
      for (int s = 1; s < RESC; ++s)
        if (rv[s] > mv || (rv[s] == mv && ri[s] < mi)) { mv = rv[s]; mi = ri[s]; }
      cv8[k] = mv; ci8[k] = mi;
      #pragma unroll
      for (int s = 0; s < RESC; ++s)
        if (ri[s] == mi) rv[s] = NEG_BIG;
    }
    float m = cv8[0];
    float wv[TK]; float sum = 0.0f;
    #pragma unroll
    for (int k = 0; k < TK; ++k) { wv[k] = expf(10.0f * (cv8[k] - m)); sum += wv[k]; }
    float rs = 1.0f / sum;
    #pragma unroll
    for (int k = 0; k < TK; ++k) { sw[k] = wv[k] * rs; sfi[k] = ci8[k]; }
  }
  __syncthreads();

  float o0 = 0.0f, o1 = 0.0f;
  #pragma unroll
  for (int s = 0; s < TK; ++s) {
    float w = sw[s];
    float2 v = *reinterpret_cast<const float2*>(&data[(size_t)sfi[s] * Dd + tid * 2]);
    o0 = fmaf(w, v.x, o0); o1 = fmaf(w, v.y, o1);
  }
  *reinterpret_cast<float2*>(&out[(size_t)qrow * Dd + tid * 2]) = float2{o0, o1};
}

extern "C" void kernel_launch(void* const* d_in, const int* in_sizes, int n_in,
                              void* d_out, int out_size, void* d_ws, size_t ws_size,
                              hipStream_t stream) {
  (void)in_sizes; (void)n_in; (void)out_size; (void)ws_size;
  const float* query = (const float*)d_in[0];
  const float* addr  = (const float*)d_in[1];
  const float* data  = (const float*)d_in[2];
  const float* W     = (const float*)d_in[3];
  const float* bias  = (const float*)d_in[4];
  float* out = (float*)d_out;

  // ws: 8.25 MB (R4-proven layout: q 4MB | inv 256KB | cand 4MB)
  char* ws = (char*)d_ws;
  size_t off = 0;
  float* q = (float*)(ws + off);            off += (size_t)Bq * Aa * 4;
  float* inv = (float*)(ws + off);          off += (size_t)Nn * 4;
  unsigned int* cand = (unsigned int*)(ws + off);
  // bf16 q lives in d_out (2MB of 4MB); merge_rescore overwrites d_out afterwards
  unsigned short* qb = (unsigned short*)d_out;

  proj_kernel<<<dim3(Aa / 64, Bq / 64), 256, 0, stream>>>(query, W, bias, q);
  norm_rows_q_kernel<<<Bq, 256, 0, stream>>>(q, qb);
  addr_inv_kernel<<<Nn / 4, 256, 0, stream>>>(addr, inv);
  sim_topk_mfma<<<dim3(NSPLIT, Bq / 128), 256, 0, stream>>>(qb, addr, inv, cand);
  merge_rescore_kernel<<<Bq, 256, 0, stream>>>(cand, q, addr, inv, data, out);
}

// Round 6
// 336.877 us; speedup vs baseline: 7.6440x; 1.2628x over previous
//
#include <hip/hip_runtime.h>

#define Bq 2048
#define Nn 65536
#define Aa 512
#define Dd 512
#define TK 8
#define NSPLIT 128
#define NSLICE 512      // Nn / NSPLIT
#define MSPLIT 4        // per-thread candidates per (split, col-half) before end-merge
#define KEEP 4          // packed candidates stored per (query, split)
#define NCAND (NSPLIT * KEEP)   // 512 per query (ws layout identical to R4/R5)
#define RESC 16         // rescored candidates per query
#define NEG_BIG (-1e38f)

typedef __attribute__((ext_vector_type(8))) short short8v;   // 8 bf16
typedef __attribute__((ext_vector_type(4))) float float4v;   // MFMA acc

__device__ __forceinline__ float wave_reduce_sum(float v) {
  #pragma unroll
  for (int o = 32; o > 0; o >>= 1) v += __shfl_down(v, o, 64);
  return v;
}

__device__ __forceinline__ unsigned short f2bf(float f) {  // RNE fp32->bf16
  unsigned int u = __float_as_uint(f);
  unsigned int r = (u + 0x7fffu + ((u >> 16) & 1u)) >> 16;
  return (unsigned short)r;
}

__device__ __forceinline__ unsigned cvt_pk(float lo, float hi) {
  unsigned r;
  asm("v_cvt_pk_bf16_f32 %0, %1, %2" : "=v"(r) : "v"(lo), "v"(hi));
  return r;
}

__device__ __forceinline__ void async16(const void* g, void* l) {
  __builtin_amdgcn_global_load_lds((const __attribute__((address_space(1))) void*)g,
                                   (__attribute__((address_space(3))) void*)l, 16, 0, 0);
}

// ---------------- Kernel 1: proj = query @ W.T + b ----------------
__global__ __launch_bounds__(256)
void proj_kernel(const float* __restrict__ query, const float* __restrict__ W,
                 const float* __restrict__ bias, float* __restrict__ proj) {
  __shared__ float Qs[32][64];
  __shared__ float Ws[32][64];
  const int obase = blockIdx.x * 64;
  const int qbase = blockIdx.y * 64;
  const int tid = threadIdx.x;
  const int ty = tid >> 4, tx = tid & 15;
  const int r0 = ty * 4, c0 = tx * 4;
  float acc[4][4] = {};
  for (int kc = 0; kc < Aa; kc += 32) {
    __syncthreads();
    #pragma unroll
    for (int i = 0; i < 2; ++i) {
      int f4 = tid + i * 256;
      int row = f4 >> 3, k4 = (f4 & 7) * 4;
      float4 qv = *reinterpret_cast<const float4*>(&query[(size_t)(qbase + row) * Aa + kc + k4]);
      Qs[k4 + 0][row] = qv.x; Qs[k4 + 1][row] = qv.y; Qs[k4 + 2][row] = qv.z; Qs[k4 + 3][row] = qv.w;
      float4 wv = *reinterpret_cast<const float4*>(&W[(size_t)(obase + row) * Aa + kc + k4]);
      Ws[k4 + 0][row] = wv.x; Ws[k4 + 1][row] = wv.y; Ws[k4 + 2][row] = wv.z; Ws[k4 + 3][row] = wv.w;
    }
    __syncthreads();
    #pragma unroll
    for (int k = 0; k < 32; ++k) {
      float4 qa = *reinterpret_cast<const float4*>(&Qs[k][r0]);
      float4 wa = *reinterpret_cast<const float4*>(&Ws[k][c0]);
      float qv[4] = {qa.x, qa.y, qa.z, qa.w};
      float wv[4] = {wa.x, wa.y, wa.z, wa.w};
      #pragma unroll
      for (int i = 0; i < 4; ++i)
        #pragma unroll
        for (int j = 0; j < 4; ++j)
          acc[i][j] = fmaf(qv[i], wv[j], acc[i][j]);
    }
  }
  float4 bv = *reinterpret_cast<const float4*>(&bias[obase + c0]);
  #pragma unroll
  for (int i = 0; i < 4; ++i) {
    float4 o;
    o.x = acc[i][0] + bv.x; o.y = acc[i][1] + bv.y;
    o.z = acc[i][2] + bv.z; o.w = acc[i][3] + bv.w;
    *reinterpret_cast<float4*>(&proj[(size_t)(qbase + r0 + i) * Aa + obase + c0]) = o;
  }
}

// ---------------- Kernel 2: normalize q rows in place, emit bf16 copy ----------------
__global__ __launch_bounds__(256)
void norm_rows_q_kernel(float* __restrict__ proj, unsigned short* __restrict__ qb) {
  const int row = blockIdx.x;
  const int tid = threadIdx.x;
  float2 v = *reinterpret_cast<float2*>(&proj[(size_t)row * Aa + tid * 2]);
  float ss = v.x * v.x + v.y * v.y;
  __shared__ float red[4];
  ss = wave_reduce_sum(ss);
  if ((tid & 63) == 0) red[tid >> 6] = ss;
  __syncthreads();
  float tot = red[0] + red[1] + red[2] + red[3];
  float scale = 1.0f / fmaxf(sqrtf(tot), 1e-12f);
  v.x *= scale; v.y *= scale;
  *reinterpret_cast<float2*>(&proj[(size_t)row * Aa + tid * 2]) = v;
  unsigned int packed = (unsigned int)f2bf(v.x) | ((unsigned int)f2bf(v.y) << 16);
  *reinterpret_cast<unsigned int*>(&qb[(size_t)row * Aa + tid * 2]) = packed;
}

// ---------------- Kernel 3: inverse norms of addr rows ----------------
__global__ __launch_bounds__(256)
void addr_inv_kernel(const float* __restrict__ addr, float* __restrict__ inv) {
  const int wid = threadIdx.x >> 6, lane = threadIdx.x & 63;
  const int row = blockIdx.x * 4 + wid;
  const float4* p = reinterpret_cast<const float4*>(&addr[(size_t)row * Aa + lane * 8]);
  float4 a = p[0], b = p[1];
  float ss = a.x * a.x + a.y * a.y + a.z * a.z + a.w * a.w
           + b.x * b.x + b.y * b.y + b.z * b.z + b.w * b.w;
  ss = wave_reduce_sum(ss);
  if (lane == 0) inv[row] = 1.0f / fmaxf(sqrtf(ss), 1e-12f);
}

// ---------------- Kernel 4: bf16 MFMA sim GEMM + fused approx top-4 ----------------
// 128x128 tile, BK=32, 4 waves (2x2 of 64x64), mfma_f32_16x16x32_bf16.
// B staged UN-normalized (pure cvt_pk); inv applied at epilogue write.
// Top-k on u16 monotone keys (sign-flipped truncated fp32) -> integer scan.
// grid (NSPLIT=128, 16) = 2048 blocks; LDS 24.8 KB.
__global__ __launch_bounds__(256, 4)
void sim_topk_mfma(const unsigned short* __restrict__ qb,
                   const float* __restrict__ addrf,
                   const float* __restrict__ inv,
                   unsigned int* __restrict__ cand) {
  __shared__ __align__(16) unsigned short Asb[128 * 32];
  __shared__ __align__(16) unsigned short Bsb[128 * 32];
  __shared__ unsigned short stageh[128][33];

  const int ns = blockIdx.x;
  const int qbase = blockIdx.y * 128;
  const int nbase0 = ns * NSLICE;
  const int tid = threadIdx.x;
  const int lane = tid & 63;
  const int wid = tid >> 6;
  const int wr = wid >> 1, wc = wid & 1;
  const int l15 = lane & 15, l4 = lane >> 4;

  // A staging (glld): 512 granule-slots; dest linear in f, src granule = phys ^ swz(row)
  const int f0 = tid, f1 = tid + 256;
  const int row0 = f0 >> 2, kl0 = (f0 & 3) ^ ((row0 >> 1) & 3);
  const int row1 = f1 >> 2, kl1 = (f1 & 3) ^ ((row1 >> 1) & 3);

  // B staging: thread t stages row brow, k-half bh (16 floats -> 2 bf16 granules)
  const int brow = tid >> 1, bh = tid & 1;
  const int bswz = (brow >> 1) & 3;
  const int bg0 = (bh * 2) ^ bswz, bg1 = (bh * 2 + 1) ^ bswz;

  unsigned tv[MSPLIT];
  #pragma unroll
  for (int s = 0; s < MSPLIT; ++s) tv[s] = 0u;
  unsigned th = 0u;

  for (int nt = 0; nt < NSLICE / 128; ++nt) {
    const int nbase = nbase0 + nt * 128;
    float4v acc[4][4];
    #pragma unroll
    for (int m = 0; m < 4; ++m)
      #pragma unroll
      for (int n = 0; n < 4; ++n) acc[m][n] = (float4v)0.0f;

    for (int kc = 0; kc < Aa; kc += 32) {
      // issue B fp32 loads before the barrier (latency overlaps prior phase tail)
      const float4* bp = reinterpret_cast<const float4*>(&addrf[(size_t)(nbase + brow) * Aa + kc + bh * 16]);
      float4 c0 = bp[0], c1 = bp[1], c2 = bp[2], c3 = bp[3];
      __syncthreads();  // prev phase's LDS reads done; safe to overwrite
      async16(&qb[(size_t)(qbase + row0) * Aa + kc + kl0 * 8], &Asb[f0 * 8]);
      async16(&qb[(size_t)(qbase + row1) * Aa + kc + kl1 * 8], &Asb[f1 * 8]);
      uint4 w0, w1;
      w0.x = cvt_pk(c0.x, c0.y); w0.y = cvt_pk(c0.z, c0.w);
      w0.z = cvt_pk(c1.x, c1.y); w0.w = cvt_pk(c1.z, c1.w);
      w1.x = cvt_pk(c2.x, c2.y); w1.y = cvt_pk(c2.z, c2.w);
      w1.z = cvt_pk(c3.x, c3.y); w1.w = cvt_pk(c3.z, c3.w);
      *reinterpret_cast<uint4*>(&Bsb[brow * 32 + bg0 * 8]) = w0;
      *reinterpret_cast<uint4*>(&Bsb[brow * 32 + bg1 * 8]) = w1;
      asm volatile("s_waitcnt vmcnt(0)" ::: "memory");  // glld A landed
      __syncthreads();  // + lgkm drain for ds_writes
      short8v a[4], b[4];
      #pragma unroll
      for (int m = 0; m < 4; ++m) {
        int ra = wr * 64 + m * 16 + l15;
        int kph = l4 ^ ((ra >> 1) & 3);
        a[m] = *reinterpret_cast<const short8v*>(&Asb[ra * 32 + kph * 8]);
      }
      #pragma unroll
      for (int n = 0; n < 4; ++n) {
        int rb = wc * 64 + n * 16 + l15;
        int kph = l4 ^ ((rb >> 1) & 3);
        b[n] = *reinterpret_cast<const short8v*>(&Bsb[rb * 32 + kph * 8]);
      }
      #pragma unroll
      for (int m = 0; m < 4; ++m)
        #pragma unroll
        for (int n = 0; n < 4; ++n)
          acc[m][n] = __builtin_amdgcn_mfma_f32_16x16x32_bf16(a[m], b[n], acc[m][n], 0, 0, 0);
    }

    // epilogue: 4 chunks of 32 cols; writer applies inv and emits u16 monotone keys.
    // C/D layout col=lane&15, row=(lane>>4)*4+reg
    #pragma unroll
    for (int ch = 0; ch < 4; ++ch) {
      __syncthreads();
      if (wc == (ch >> 1)) {
        #pragma unroll
        for (int nl = 0; nl < 2; ++nl) {
          int n = (ch & 1) * 2 + nl;
          float ivv = inv[nbase + ch * 32 + nl * 16 + l15];
          #pragma unroll
          for (int m = 0; m < 4; ++m)
            #pragma unroll
            for (int j = 0; j < 4; ++j) {
              float v = acc[m][n][j] * ivv;
              unsigned t = __float_as_uint(v) >> 16;
              unsigned key = t ^ ((t & 0x8000u) ? 0xFFFFu : 0x8000u);
              stageh[wr * 64 + m * 16 + l4 * 4 + j][nl * 16 + l15] = (unsigned short)key;
            }
        }
      }
      __syncthreads();
      const int r = tid & 127, hh = tid >> 7;
      const int gb = nbase + ch * 32 + hh * 16;
      #pragma unroll 4
      for (int j = 0; j < 16; ++j) {
        unsigned key = stageh[r][hh * 16 + j];
        unsigned p = (key << 16) | (unsigned)(gb + j);
        if (p > th) {
          unsigned mv = tv[0];
          #pragma unroll
          for (int s = 1; s < MSPLIT; ++s) mv = min(mv, tv[s]);
          bool done = false;
          #pragma unroll
          for (int s = 0; s < MSPLIT; ++s)
            if (!done && tv[s] == mv) { tv[s] = p; done = true; }
          th = tv[0];
          #pragma unroll
          for (int s = 1; s < MSPLIT; ++s) th = min(th, tv[s]);
        }
      }
    }
  }

  // end-merge 2 col-half buckets -> top-4 per (query, split); tv already packed
  unsigned* mg = reinterpret_cast<unsigned*>(&stageh[0][0]);
  __syncthreads();  // all scans done before overwriting stageh
  {
    const int r = tid & 127, hh = tid >> 7;
    #pragma unroll
    for (int s = 0; s < MSPLIT; ++s) mg[r * 8 + hh * 4 + s] = tv[s];
  }
  __syncthreads();
  if (tid < 128) {
    unsigned v[8];
    #pragma unroll
    for (int s = 0; s < 8; ++s) v[s] = mg[tid * 8 + s];
    size_t base = ((size_t)(qbase + tid) * NSPLIT + ns) * KEEP;
    #pragma unroll
    for (int k = 0; k < KEEP; ++k) {
      unsigned M = v[0];
      #pragma unroll
      for (int s = 1; s < 8; ++s) M = (v[s] > M) ? v[s] : M;
      cand[base + k] = M;
      #pragma unroll
      for (int s = 0; s < 8; ++s) if (v[s] == M) v[s] = 0u;
    }
  }
}

// ---------------- Kernel 5: merge 512 -> approx top-16 -> fp32 rescore -> top-8 -> out ----------------
__global__ __launch_bounds__(256)
void merge_rescore_kernel(const unsigned int* __restrict__ cand,
                          const float* __restrict__ q, const float* __restrict__ addrf,
                          const float* __restrict__ inv, const float* __restrict__ data,
                          float* __restrict__ out) {
  const int qrow = blockIdx.x;
  const int tid = threadIdx.x;
  const int wid = tid >> 6, lane = tid & 63;
  __shared__ int sidx[RESC];
  __shared__ float resc[RESC];
  __shared__ float sw[TK]; __shared__ int sfi[TK];

  // wave 0: top-16 of 512 packed candidates (64 lanes x 8 regs, 16 reduce-clear iters)
  if (wid == 0) {
    const unsigned* cv = &cand[(size_t)qrow * NCAND];
    uint4 t0 = *reinterpret_cast<const uint4*>(&cv[lane * 8]);
    uint4 t1 = *reinterpret_cast<const uint4*>(&cv[lane * 8 + 4]);
    unsigned v[8] = {t0.x, t0.y, t0.z, t0.w, t1.x, t1.y, t1.z, t1.w};
    #pragma unroll
    for (int it = 0; it < RESC; ++it) {
      unsigned m = v[0];
      #pragma unroll
      for (int s = 1; s < 8; ++s) m = (v[s] > m) ? v[s] : m;
      #pragma unroll
      for (int off = 1; off < 64; off <<= 1) {
        unsigned o_ = (unsigned)__shfl_xor((int)m, off, 64);
        m = (o_ > m) ? o_ : m;
      }
      if (lane == 0) sidx[it] = (int)(m & 0xFFFFu);
      #pragma unroll
      for (int s = 0; s < 8; ++s) if (v[s] == m) v[s] = 0u;
    }
  }
  __syncthreads();

  // exact fp32 rescore of 16 candidates: wave w handles c = w*4 + it
  float4 q0 = *reinterpret_cast<const float4*>(&q[(size_t)qrow * Aa + lane * 8]);
  float4 q1 = *reinterpret_cast<const float4*>(&q[(size_t)qrow * Aa + lane * 8 + 4]);
  #pragma unroll
  for (int it = 0; it < RESC / 4; ++it) {
    int c = wid * 4 + it;
    int idx = sidx[c];
    const float4* ap = reinterpret_cast<const float4*>(&addrf[(size_t)idx * Aa + lane * 8]);
    float4 a0 = ap[0], a1 = ap[1];
    float s = q0.x * a0.x + q0.y * a0.y + q0.z * a0.z + q0.w * a0.w
            + q1.x * a1.x + q1.y * a1.y + q1.z * a1.z + q1.w * a1.w;
    s = wave_reduce_sum(s);
    if (lane == 0) resc[c] = s * inv[idx];
  }
  __syncthreads();

  if (tid == 0) {
    float rv[RESC]; int ri[RESC];
    #pragma unroll
    for (int s = 0; s < RESC; ++s) { rv[s] = resc[s]; ri[s] = sidx[s]; }
    float cv8[TK]; int ci8[TK];
    #pragma unroll
    for (int k = 0; k < TK; ++k) {
      float mv = rv[0]; int mi = ri[0];
      #pragma unroll
      for (int s = 1; s < RESC; ++s)
        if (rv[s] > mv || (rv[s] == mv && ri[s] < mi)) { mv = rv[s]; mi = ri[s]; }
      cv8[k] = mv; ci8[k] = mi;
      #pragma unroll
      for (int s = 0; s < RESC; ++s)
        if (ri[s] == mi) rv[s] = NEG_BIG;
    }
    float m = cv8[0];
    float wv[TK]; float sum = 0.0f;
    #pragma unroll
    for (int k = 0; k < TK; ++k) { wv[k] = expf(10.0f * (cv8[k] - m)); sum += wv[k]; }
    float rs = 1.0f / sum;
    #pragma unroll
    for (int k = 0; k < TK; ++k) { sw[k] = wv[k] * rs; sfi[k] = ci8[k]; }
  }
  __syncthreads();

  float o0 = 0.0f, o1 = 0.0f;
  #pragma unroll
  for (int s = 0; s < TK; ++s) {
    float w = sw[s];
    float2 v = *reinterpret_cast<const float2*>(&data[(size_t)sfi[s] * Dd + tid * 2]);
    o0 = fmaf(w, v.x, o0); o1 = fmaf(w, v.y, o1);
  }
  *reinterpret_cast<float2*>(&out[(size_t)qrow * Dd + tid * 2]) = float2{o0, o1};
}

extern "C" void kernel_launch(void* const* d_in, const int* in_sizes, int n_in,
                              void* d_out, int out_size, void* d_ws, size_t ws_size,
                              hipStream_t stream) {
  (void)in_sizes; (void)n_in; (void)out_size; (void)ws_size;
  const float* query = (const float*)d_in[0];
  const float* addr  = (const float*)d_in[1];
  const float* data  = (const float*)d_in[2];
  const float* W     = (const float*)d_in[3];
  const float* bias  = (const float*)d_in[4];
  float* out = (float*)d_out;

  // ws: 8.25 MB (proven layout: q 4MB | inv 256KB | cand 4MB)
  char* ws = (char*)d_ws;
  size_t off = 0;
  float* q = (float*)(ws + off);            off += (size_t)Bq * Aa * 4;
  float* inv = (float*)(ws + off);          off += (size_t)Nn * 4;
  unsigned int* cand = (unsigned int*)(ws + off);
  // bf16 q lives in d_out (2MB of 4MB); merge_rescore overwrites d_out afterwards
  unsigned short* qb = (unsigned short*)d_out;

  proj_kernel<<<dim3(Aa / 64, Bq / 64), 256, 0, stream>>>(query, W, bias, q);
  norm_rows_q_kernel<<<Bq, 256, 0, stream>>>(q, qb);
  addr_inv_kernel<<<Nn / 4, 256, 0, stream>>>(addr, inv);
  sim_topk_mfma<<<dim3(NSPLIT, Bq / 128), 256, 0, stream>>>(qb, addr, inv, cand);
  merge_rescore_kernel<<<Bq, 256, 0, stream>>>(cand, q, addr, inv, data, out);
}